// Round 1
// baseline (127114.478 us; speedup 1.0000x reference)
//
#include <hip/hip_runtime.h>
#include <math.h>

// One batch per block. Zero inter-block communication: the 8 batch lanes of
// the reference are fully independent (argmax feeds back only into its own
// batch). All state lives in LDS; dilation rings in block-private workspace;
// weights (~8.1 MB/timestep) stream from global (L3-resident, per-XCD L2 hot).

#define TT 512
#define NBLK 8
#define NTHR 1024

typedef float f4 __attribute__((ext_vector_type(4)));

__constant__ int c_dil[20]  = {1,2,4,8,16,32,64,128,256,512,
                               1,2,4,8,16,32,64,128,256,512};
// float offsets of each layer's ring within a block's 262144-float region
__constant__ int c_roff[20] = {0,128,384,896,1920,3968,8064,16256,32640,65408,
                               130944,131072,131328,131840,132864,134912,
                               139008,147200,163584,196352};

// ---------------- LDS layout (float offsets) ----------------
#define CONDZ  0        // [20][256] per-chunk cond+biases folded z offset
#define RESB   5120     // [20][128]
#define SKIPB  7680     // [20][128]
#define SFC    10240    // [128] fc_b + condf_b + condf_w.c
#define PREV   10368    // [2][128] double-buffered prev (ring read-ahead)
#define RES    10624    // [128] running residual
#define HH     10752    // [128] h
#define SKIP   10880    // [128] skip accumulator
#define SV     11008    // [128] relu(s)
#define LOG    11136    // [256] logits
#define CVEC   11392    // [64]  c for this chunk
#define FW0    11456    // [128] first_w[:,0,0]
#define FW1    11584    // [128] first_w[:,0,1]
#define FB     11712    // [128]
#define SKIPCB 11840    // [128]
#define LOGB   11968    // [256]
#define XS     12224    // [3] xcur, xprev, (scratch)
#define PSZ    12240

__device__ __forceinline__ float dot4(f4 w, f4 x) {
    return w.x*x.x + w.y*x.y + w.z*x.z + w.w*x.w;
}

__global__ __launch_bounds__(NTHR, 4) void wn_gen(
    const float* __restrict__ enc,
    const float* __restrict__ first_w,  const float* __restrict__ first_b,
    const float* __restrict__ causal_w, const float* __restrict__ causal_b,
    const float* __restrict__ cond_w,   const float* __restrict__ cond_b,
    const float* __restrict__ res_w,    const float* __restrict__ res_b,
    const float* __restrict__ skip_w,   const float* __restrict__ skip_b,
    const float* __restrict__ skipc_w,  const float* __restrict__ skipc_b,
    const float* __restrict__ fc_w,     const float* __restrict__ fc_b,
    const float* __restrict__ condf_w,  const float* __restrict__ condf_b,
    const float* __restrict__ logits_w, const float* __restrict__ logits_b,
    float* __restrict__ wsf, float* __restrict__ out)
{
    __shared__ __align__(16) float P[PSZ];
    const int tid = threadIdx.x;
    const int b = blockIdx.x;
    float* ringb = wsf + (size_t)b * 262144;   // block-private ring region

    // ---------------- init: small LDS-resident params ----------------
    for (int m = tid; m < 2560; m += NTHR) {
        P[RESB + m]  = res_b[m];
        P[SKIPB + m] = skip_b[m];
    }
    if (tid < 128) {
        P[FW0 + tid]    = first_w[2*tid];
        P[FW1 + tid]    = first_w[2*tid + 1];
        P[FB + tid]     = first_b[tid];
        P[SKIPCB + tid] = skipc_b[tid];
    }
    if (tid < 256) P[LOGB + tid] = logits_b[tid];
    if (tid == 0) { P[XS] = 128.f/255.f - 0.5f; P[XS+1] = 0.f; }
    __syncthreads();

    for (int t = 0; t < TT; ++t) {
        // ---------------- per-chunk precompute (every 64 steps) ----------------
        if ((t & 63) == 0) {
            const int te = t >> 6;
            if (tid < 64) P[CVEC + tid] = enc[(size_t)(b*64 + tid)*8 + te];
            __syncthreads();
            {
                const f4* c4 = (const f4*)&P[CVEC];
                #pragma unroll
                for (int ph = 0; ph < 5; ++ph) {
                    int row = ph*1024 + tid;               // (l,g): l=row>>8
                    const f4* w4 = (const f4*)(cond_w + (size_t)row*64);
                    float acc = causal_b[row] + cond_b[row];
                    #pragma unroll 4
                    for (int k = 0; k < 16; ++k) acc += dot4(w4[k], c4[k]);
                    P[CONDZ + row] = acc;
                }
                if (tid < 128) {
                    const f4* w4 = (const f4*)(condf_w + (size_t)tid*64);
                    float acc = fc_b[tid] + condf_b[tid];
                    #pragma unroll 4
                    for (int k = 0; k < 16; ++k) acc += dot4(w4[k], c4[k]);
                    P[SFC + tid] = acc;
                }
            }
            __syncthreads();
        }

        const int lane6 = tid & 63, wv = tid >> 6;

        // ---------------- prologue A: res0 + ring0 read ----------------
        if (tid < 128)
            P[RES + tid] = P[XS+1]*P[FW0+tid] + P[XS]*P[FW1+tid] + P[FB+tid];
        if (lane6 >= 2 && lane6 < 4) {                 // 2 lanes of each wave
            int k = wv*2 + (lane6 - 2);                // k in 0..31
            f4 v = {0.f, 0.f, 0.f, 0.f};
            if (t >= 1) v = *(const f4*)(ringb + 4*k); // ring0: d=1, slot 0
            *(f4*)&P[PREV + 4*k] = v;                  // parity 0 for layer 0
        }
        __syncthreads();

        // ---------------- prologue B: skip init (skipc_w . res0) ----------------
        {
            int r = tid >> 3, cc = tid & 7;
            const f4* w4 = (const f4*)(skipc_w + (size_t)r*128 + cc*16);
            const f4* x4 = (const f4*)&P[RES + cc*16];
            float acc = 0.f;
            #pragma unroll
            for (int k = 0; k < 4; ++k) acc += dot4(w4[k], x4[k]);
            acc += __shfl_xor(acc, 1); acc += __shfl_xor(acc, 2); acc += __shfl_xor(acc, 4);
            if (cc == 0) P[SKIP + r] = acc + P[SKIPCB + r];
        }
        __syncthreads();

        // ---------------- layer loop: 2 barriers per layer ----------------
        for (int l = 0; l < 20; ++l) {
            const int par = l & 1;
            // ---- z-phase: z = W0.prev + W1.res + condz -> h (fused) ----
            {
                // ring ops, spread 4 lanes per wave (issue early, overlap FMAs)
                if (lane6 < 2) {
                    int k = wv*2 + lane6;
                    int d = c_dil[l], slot = t & (d - 1);
                    *(f4*)(ringb + c_roff[l] + (size_t)slot*128 + 4*k) =
                        *(const f4*)&P[RES + 4*k];            // store layer input
                } else if (lane6 < 4 && l < 19) {
                    int k = wv*2 + (lane6 - 2);
                    int d = c_dil[l+1], slot = t & (d - 1);
                    f4 v = {0.f, 0.f, 0.f, 0.f};
                    if (t >= d)
                        v = *(const f4*)(ringb + c_roff[l+1] + (size_t)slot*128 + 4*k);
                    *(f4*)&P[PREV + (par^1)*128 + 4*k] = v;   // prev for layer l+1
                }
                // thread t: gate row p and out row p+128, cols cc*16..+15
                int p = tid >> 3, cc = tid & 7;
                // causal_w[l][row][col][{0,1}]: one f4 = {W0[c],W1[c],W0[c+1],W1[c+1]}
                const f4* wg4 = (const f4*)(causal_w + (size_t)(l*256 + p)*256 + cc*32);
                const f4* wo4 = wg4 + 128*64;   // +128 rows * 64 f4/row
                const f4* pv4 = (const f4*)&P[PREV + par*128 + cc*16];
                const f4* rv4 = (const f4*)&P[RES + cc*16];
                float accg = 0.f, acco = 0.f;
                #pragma unroll
                for (int k = 0; k < 4; ++k) {
                    f4 pa = pv4[k], ra = rv4[k];
                    f4 g0 = wg4[2*k], g1 = wg4[2*k+1];
                    f4 o0 = wo4[2*k], o1 = wo4[2*k+1];
                    accg += g0.x*pa.x + g0.y*ra.x + g0.z*pa.y + g0.w*ra.y;
                    accg += g1.x*pa.z + g1.y*ra.z + g1.z*pa.w + g1.w*ra.w;
                    acco += o0.x*pa.x + o0.y*ra.x + o0.z*pa.y + o0.w*ra.y;
                    acco += o1.x*pa.z + o1.y*ra.z + o1.z*pa.w + o1.w*ra.w;
                }
                accg += __shfl_xor(accg, 1); accg += __shfl_xor(accg, 2); accg += __shfl_xor(accg, 4);
                acco += __shfl_xor(acco, 1); acco += __shfl_xor(acco, 2); acco += __shfl_xor(acco, 4);
                if (cc == 0) {
                    float g = accg + P[CONDZ + l*256 + p];
                    float o = acco + P[CONDZ + l*256 + 128 + p];
                    P[HH + p] = (1.f/(1.f + expf(-g))) * tanhf(o);
                }
            }
            __syncthreads();
            // ---- rs-phase: res += h.res_w^T + res_b ; skip += h.skip_w^T + skip_b ----
            {
                int r = tid >> 3, cc = tid & 7;
                const f4* h4 = (const f4*)&P[HH + cc*16];
                f4 h0 = h4[0], h1 = h4[1], h2 = h4[2], h3 = h4[3];
                const f4* sw4 = (const f4*)(skip_w + ((size_t)l*128 + r)*128 + cc*16);
                float acs = dot4(sw4[0], h0) + dot4(sw4[1], h1)
                          + dot4(sw4[2], h2) + dot4(sw4[3], h3);
                acs += __shfl_xor(acs, 1); acs += __shfl_xor(acs, 2); acs += __shfl_xor(acs, 4);
                if (l < 19) {   // res_{20} is never consumed
                    const f4* rw4 = (const f4*)(res_w + ((size_t)l*128 + r)*128 + cc*16);
                    float acr = dot4(rw4[0], h0) + dot4(rw4[1], h1)
                              + dot4(rw4[2], h2) + dot4(rw4[3], h3);
                    acr += __shfl_xor(acr, 1); acr += __shfl_xor(acr, 2); acr += __shfl_xor(acr, 4);
                    if (cc == 0) P[RES + r] += acr + P[RESB + l*128 + r];
                }
                if (cc == 0) P[SKIP + r] += acs + P[SKIPB + l*128 + r];
            }
            __syncthreads();
        }

        // ---------------- head: s = relu(skip).fc^T + sfc ----------------
        {
            int r = tid >> 3, cc = tid & 7;
            const f4* w4 = (const f4*)(fc_w + (size_t)r*128 + cc*16);
            const f4* k4 = (const f4*)&P[SKIP + cc*16];
            float acc = 0.f;
            #pragma unroll
            for (int k = 0; k < 4; ++k) {
                f4 w = w4[k], x = k4[k];
                acc += w.x*fmaxf(x.x, 0.f) + w.y*fmaxf(x.y, 0.f)
                     + w.z*fmaxf(x.z, 0.f) + w.w*fmaxf(x.w, 0.f);
            }
            acc += __shfl_xor(acc, 1); acc += __shfl_xor(acc, 2); acc += __shfl_xor(acc, 4);
            if (cc == 0) P[SV + r] = fmaxf(acc + P[SFC + r], 0.f);  // store relu(s)
        }
        __syncthreads();
        // ---------------- logits = relu(s).logits_w^T + logits_b ----------------
        {
            int q = tid >> 2, c2 = tid & 3;
            const f4* w4 = (const f4*)(logits_w + (size_t)q*128 + c2*32);
            const f4* s4 = (const f4*)&P[SV + c2*32];
            float acc = 0.f;
            #pragma unroll
            for (int k = 0; k < 8; ++k) acc += dot4(w4[k], s4[k]);
            acc += __shfl_xor(acc, 1); acc += __shfl_xor(acc, 2);
            if (c2 == 0) P[LOG + q] = acc + P[LOGB + q];
        }
        __syncthreads();
        // ---------------- argmax (first-max tie-break) + outputs + x shift ----------------
        if (tid < 64) {
            float best = -3.4e38f; int bi = 0;
            #pragma unroll
            for (int s0 = 0; s0 < 4; ++s0) {
                int q = s0*64 + tid;          // ascending -> keeps first max
                float v = P[LOG + q];
                if (v > best) { best = v; bi = q; }
            }
            #pragma unroll
            for (int m = 32; m >= 1; m >>= 1) {
                float ov = __shfl_xor(best, m);
                int   oi = __shfl_xor(bi, m);
                if (ov > best || (ov == best && oi < bi)) { best = ov; bi = oi; }
            }
            if (tid == 0) {
                float nb = (float)bi;
                out[t*8 + b] = nb;                         // samples region
                P[XS+1] = P[XS];                           // xprev = xcur
                P[XS]   = nb*(1.f/255.f) - 0.5f;           // xcur from new sample
            }
        } else if (tid < 128) {
            int k = tid - 64;                              // coalesced logits store
            *(f4*)(out + 4096 + ((size_t)(t*8 + b))*256 + 4*k) =
                *(const f4*)&P[LOG + 4*k];
        }
        __syncthreads();
    }
}

// ============================================================
extern "C" void kernel_launch(void* const* d_in, const int* in_sizes, int n_in,
                              void* d_out, int out_size, void* d_ws, size_t ws_size,
                              hipStream_t stream) {
    const float* enc      = (const float*)d_in[0];
    const float* first_w  = (const float*)d_in[1];
    const float* first_b  = (const float*)d_in[2];
    const float* causal_w = (const float*)d_in[3];
    const float* causal_b = (const float*)d_in[4];
    const float* cond_w   = (const float*)d_in[5];
    const float* cond_b   = (const float*)d_in[6];
    const float* res_w    = (const float*)d_in[7];
    const float* res_b    = (const float*)d_in[8];
    const float* skip_w   = (const float*)d_in[9];
    const float* skip_b   = (const float*)d_in[10];
    const float* skipc_w  = (const float*)d_in[11];
    const float* skipc_b  = (const float*)d_in[12];
    const float* fc_w     = (const float*)d_in[13];
    const float* fc_b     = (const float*)d_in[14];
    const float* condf_w  = (const float*)d_in[15];
    const float* condf_b  = (const float*)d_in[16];
    const float* logits_w = (const float*)d_in[17];
    const float* logits_b = (const float*)d_in[18];

    float* wsf = (float*)d_ws;
    float* out = (float*)d_out;

    wn_gen<<<NBLK, NTHR, 0, stream>>>(
        enc, first_w, first_b, causal_w, causal_b, cond_w, cond_b,
        res_w, res_b, skip_w, skip_b, skipc_w, skipc_b, fc_w, fc_b,
        condf_w, condf_b, logits_w, logits_b, wsf, out);
}

// Round 2
// 35988.300 us; speedup vs baseline: 3.5321x; 3.5321x over previous
//
#include <hip/hip_runtime.h>
#include <math.h>

// ---------------- problem constants ----------------
#define BB 8
#define TT 512
#define LL 20
#define NBLK 64
#define NTHR 256

typedef float f4 __attribute__((ext_vector_type(4)));
typedef unsigned long long ull;

__constant__ int c_dil[LL] = {1,2,4,8,16,32,64,128,256,512,
                              1,2,4,8,16,32,64,128,256,512};
// double-buffered rings: layer l has 2*d slots of 1024 floats (ring[0] unused)
__constant__ int c_roff[LL] = {-1,0,4096,12288,28672,61440,126976,258048,520192,1044480,
                               2093056,2095104,2099200,2107392,2123776,2156544,
                               2222080,2353152,2615296,3139584};

// ---------------- workspace layout (floats) ----------------
constexpr size_t OFF_RING = 0;          // 4,188,160 floats
constexpr size_t OFF_X    = 4188160;    // exchange: 4 slots * 768 float4

// ---------------- LDS pool offsets (floats) ----------------
#define P_WC     0        // [20][4][256]: z-row g: [0:128]=W0(prev) [128:256]=W1(res)
#define P_F      20480    // [19][4][128]: F_l = W1_{l+1}slice . Wres_l^T
#define P_WST    30208    // [512]: per-layer staged res/skip rows
#define P_WSKIPC 30720    // [2][128]
#define P_WFC    30976    // [2][128]
#define P_WLOG   31232    // [4][128]
#define P_WF0    31744    // [128]
#define P_WF1    31872    // [128]
#define P_FB     32000    // [128]
#define P_CONDZ  32128    // [20][4][8]  (includes zb fold)
#define P_SFC    32768    // [2][8]
#define P_RESB   32784    // [20][2]
#define P_SKIPB  32824    // [20][2]
#define P_ZB     32864    // [20][4]
#define P_LOGB   32944    // [4]
#define P_SKIPCB 32948    // [2]
#define P_Z0C    32952    // [4][6]: per g: KP, KC, U, C1, A0  (layer-0 closed form)
#define P_SKC    32976    // [2][3]: SK, SA, SB (skip-init closed form)
#define P_XS     32984    // [3][8]: x0 (=X(t)), x1 (=X(t-1)), x2 (=X(t-2))
#define P_SZ     33008    // [32]
#define P_SL     33040    // [32]
#define P_SKACC  33072    // [16]
#define P_R2     33088    // [16]
#define P_CF     33104    // [8][66]
#define P_PREVF  33632    // [8][132]
#define P_HF     34688    // [8][132]
#define P_RESF   35744    // [8][132]
#define P_RES0   36800    // [8][132]
#define POOL_FL  37856    // 151,424 bytes

// ---------------- coherent 16B exchange primitives (sc0 sc1 -> L3) ----------
__device__ __forceinline__ f4 ldx(const f4* p) {
    f4 r;
    asm volatile("global_load_dwordx4 %0, %1, off sc0 sc1\n\ts_waitcnt vmcnt(0)"
                 : "=v"(r) : "v"(p) : "memory");
    return r;
}
__device__ __forceinline__ void ldx2(const f4* p0, const f4* p1, f4& a, f4& b) {
    asm volatile("global_load_dwordx4 %0, %2, off sc0 sc1\n\t"
                 "global_load_dwordx4 %1, %3, off sc0 sc1\n\t"
                 "s_waitcnt vmcnt(0)"
                 : "=v"(a), "=v"(b) : "v"(p0), "v"(p1) : "memory");
}
__device__ __forceinline__ void ld4x(const f4* a0, const f4* a1, const f4* a2, const f4* a3,
                                     f4& r0, f4& r1, f4& r2, f4& r3) {
    asm volatile("global_load_dwordx4 %0, %4, off sc0 sc1\n\t"
                 "global_load_dwordx4 %1, %5, off sc0 sc1\n\t"
                 "global_load_dwordx4 %2, %6, off sc0 sc1\n\t"
                 "global_load_dwordx4 %3, %7, off sc0 sc1\n\t"
                 "s_waitcnt vmcnt(0)"
                 : "=v"(r0), "=v"(r1), "=v"(r2), "=v"(r3)
                 : "v"(a0), "v"(a1), "v"(a2), "v"(a3) : "memory");
}
__device__ __forceinline__ void stx(f4* p, f4 v) {
    asm volatile("global_store_dwordx4 %0, %1, off sc0 sc1"
                 :: "v"(p), "v"(v) : "memory");
}
__device__ __forceinline__ void spin(const f4* p, int e, f4& a) {
    while (__float_as_int(a.w) != e) a = ldx(p);
}

// ---- payload packing: q in 0..5, i in 0..2, V = 3q+i.
// V in [0,8)  -> value sl[V]        (r=0 half)
// V == 8, 17  -> pad
// V in [9,17) -> value sl[V-1]      (r=1 half, sl[8..15])
__device__ __forceinline__ float pick16(const float* sl, int V) {
    if (V < 8) return sl[V];
    if (V >= 9 && V < 17) return sl[V - 1];
    return 0.f;
}
__device__ __forceinline__ void publish16(f4* slot, int J, const float* sl, int e) {
    if (threadIdx.x < 6) {
        int q = threadIdx.x;
        f4 v;
        v.x = pick16(sl, 3*q);
        v.y = pick16(sl, 3*q + 1);
        v.z = pick16(sl, 3*q + 2);
        v.w = __int_as_float(e);
        stx(slot + J*6 + q, v);
    }
}
// half-publish: wave holding half r (8 floats) publishes its own 3 f4 (lanes m=0..2)
__device__ __forceinline__ void publish_half(f4* slot, int J, int r, const float* half8,
                                             int e, int m) {
    int base = 3*m;
    f4 v;
    v.x = half8[base];
    v.y = (base + 1 < 8) ? half8[base + 1] : 0.f;
    v.z = (base + 2 < 8) ? half8[base + 2] : 0.f;
    v.w = __int_as_float(e);
    stx(slot + J*6 + 3*r + m, v);
}
__device__ __forceinline__ void scat16(float* dst, f4 v, int vi, bool dorelu) {
    int j = vi / 6, q = vi - 6*j;
    #pragma unroll
    for (int i = 0; i < 3; ++i) {
        int V = 3*q + i;
        float x = v[i];
        if (dorelu) x = fmaxf(x, 0.f);
        if (V < 8)                 dst[V*132 + 2*j]           = x;
        else if (V >= 9 && V < 17) dst[(V - 9)*132 + 2*j + 1] = x;
    }
}
__device__ __forceinline__ void consume16(const f4* slot, int e, float* dst, bool dorelu) {
    int m = threadIdx.x;
    const f4 *p0 = slot + m, *p1 = slot + 256 + m;
    f4 a, b;
    bool two = (m < 128);
    if (two) ldx2(p0, p1, a, b); else a = ldx(p0);
    spin(p0, e, a);
    if (two) spin(p1, e, b);
    scat16(dst, a, m, dorelu);
    if (two) scat16(dst, b, m + 256, dorelu);
}
// fused: res (published a layer ago) + h (published this layer) — one vmcnt(0) issue
__device__ __forceinline__ void consume_pair(const f4* sR, int eR, float* dR,
                                             const f4* sH, int eH, float* dH) {
    int m = threadIdx.x;
    const f4 *pra = sR + m, *prb = sR + 256 + m, *pha = sH + m, *phb = sH + 256 + m;
    f4 ra, rb, ha, hb;
    bool two = (m < 128);
    if (two) ld4x(pra, prb, pha, phb, ra, rb, ha, hb);
    else     ldx2(pra, pha, ra, ha);
    spin(pra, eR, ra);
    if (two) spin(prb, eR, rb);
    scat16(dR, ra, m, false);
    if (two) scat16(dR, rb, m + 256, false);
    spin(pha, eH, ha);
    if (two) spin(phb, eH, hb);
    scat16(dH, ha, m, false);
    if (two) scat16(dH, hb, m + 256, false);
}

// ============================================================
__global__ __launch_bounds__(NTHR, 1) void wn_gen(
    const float* __restrict__ enc,
    const float* __restrict__ first_w,  const float* __restrict__ first_b,
    const float* __restrict__ causal_w, const float* __restrict__ causal_b,
    const float* __restrict__ cond_w,   const float* __restrict__ cond_b,
    const float* __restrict__ res_w,    const float* __restrict__ res_b,
    const float* __restrict__ skip_w,   const float* __restrict__ skip_b,
    const float* __restrict__ skipc_w,  const float* __restrict__ skipc_b,
    const float* __restrict__ fc_w,     const float* __restrict__ fc_b,
    const float* __restrict__ condf_w,  const float* __restrict__ condf_b,
    const float* __restrict__ logits_w, const float* __restrict__ logits_b,
    float* __restrict__ wsf, float* __restrict__ out)
{
    extern __shared__ float pool[];
    const int tid = threadIdx.x;
    const int J = blockIdx.x;
    float* ring = wsf + OFF_RING;
    f4* xb = (f4*)(wsf + OFF_X);

    // ---------------- init: weight slices -> LDS ----------------
    for (int m = tid; m < 20480; m += NTHR) {
        int l = m >> 10, rem = m & 1023, g = rem >> 8, i = rem & 255;
        int grow = (g < 2) ? (2*J + g) : (128 + 2*J + (g - 2));
        int col = i & 127, k = i >> 7;
        pool[P_WC + m] = causal_w[((size_t)(l*256 + grow)*128 + col)*2 + k];
    }
    if (tid < 256) {
        int r = tid >> 7, i = tid & 127;
        pool[P_WSKIPC + tid] = skipc_w[(size_t)(2*J + r)*128 + i];
        pool[P_WFC + tid]    = fc_w[(size_t)(2*J + r)*128 + i];
    }
    for (int m = tid; m < 512; m += NTHR) {
        int w = m >> 7, i = m & 127;
        pool[P_WLOG + m] = logits_w[(size_t)(4*J + w)*128 + i];
    }
    if (tid < 128) {
        pool[P_WF0 + tid] = first_w[2*tid];
        pool[P_WF1 + tid] = first_w[2*tid + 1];
        pool[P_FB + tid]  = first_b[tid];
    }
    if (tid < 40) {
        int l = tid >> 1, r = tid & 1;
        pool[P_RESB + tid]  = res_b[l*128 + 2*J + r];
        pool[P_SKIPB + tid] = skip_b[l*128 + 2*J + r];
    }
    if (tid < 4) pool[P_LOGB + tid] = logits_b[4*J + tid];
    if (tid < 2) pool[P_SKIPCB + tid] = skipc_b[2*J + tid];
    if (tid < 8) {
        pool[P_XS + tid]      = 128.f/255.f - 0.5f;  // X(0)
        pool[P_XS + 8 + tid]  = 0.f;                 // X(-1)
        pool[P_XS + 16 + tid] = 0.f;                 // X(-2)
    }
    __syncthreads();   // P_WC / first-layer params ready

    // F_l[g][j] = sum_i W1_{l+1}[g][i] * res_w[l][i][j]   (l = 0..18)
    for (int l = 0; l < 19; ++l) {
        for (int m = tid; m < 512; m += NTHR) {
            int g = m >> 7, j = m & 127;
            const float* w1 = pool + P_WC + ((l+1)*4 + g)*256 + 128;
            const float* rw = res_w + (size_t)l*128*128 + j;
            float acc = 0.f;
            #pragma unroll 8
            for (int i = 0; i < 128; ++i) acc += w1[i] * rw[(size_t)i*128];
            pool[P_F + (l*4 + g)*128 + j] = acc;
        }
    }
    // zb_l[g] = W1_l[g] . res_b[l-1]  (l >= 1)
    if (tid < 80) {
        int l = tid >> 2, g = tid & 3;
        float acc = 0.f;
        if (l >= 1) {
            const float* w1 = pool + P_WC + (l*4 + g)*256 + 128;
            for (int i = 0; i < 128; ++i) acc += w1[i] * res_b[(l-1)*128 + i];
        }
        pool[P_ZB + tid] = acc;
    }
    // layer-0 closed form: z0 = kf*KP + KC + x2*U + x1*C1 + x0*A0 + condz0
    if (tid < 4) {
        const float* w0 = pool + P_WC + tid*256;
        const float* w1 = w0 + 128;
        float kp = 0.f, kc = 0.f, u = 0.f, c1 = 0.f, a0 = 0.f;
        for (int j = 0; j < 128; ++j) {
            float f0 = pool[P_WF0 + j], f1 = pool[P_WF1 + j], fbv = pool[P_FB + j];
            kp += w0[j]*fbv; kc += w1[j]*fbv;
            u  += w0[j]*f0;  c1 += w0[j]*f1 + w1[j]*f0;  a0 += w1[j]*f1;
        }
        pool[P_Z0C + tid*6 + 0] = kp;
        pool[P_Z0C + tid*6 + 1] = kc;
        pool[P_Z0C + tid*6 + 2] = u;
        pool[P_Z0C + tid*6 + 3] = c1;
        pool[P_Z0C + tid*6 + 4] = a0;
    }
    // skip-init closed form: skip0 = SK + x1*SA + x0*SB
    if (tid < 2) {
        const float* wr = pool + P_WSKIPC + tid*128;
        float sk = pool[P_SKIPCB + tid], sa = 0.f, sb = 0.f;
        for (int j = 0; j < 128; ++j) {
            sk += wr[j]*pool[P_FB + j];
            sa += wr[j]*pool[P_WF0 + j];
            sb += wr[j]*pool[P_WF1 + j];
        }
        pool[P_SKC + tid*3 + 0] = sk;
        pool[P_SKC + tid*3 + 1] = sa;
        pool[P_SKC + tid*3 + 2] = sb;
    }
    __syncthreads();

    int e = 0;            // exchange epoch (uniform ++ order across all blocks)
    int er_pending = 0;   // epoch of most recent res publish
    int esk = 0;          // epoch of skip publish (set at l==19)

    for (int t = 0; t < TT; ++t) {
        // ---------------- per-chunk precompute ----------------
        if ((t & 63) == 0) {
            int te = t >> 6;
            for (int m = tid; m < 512; m += NTHR) {
                int b = m >> 6, j = m & 63;
                pool[P_CF + b*66 + j] = enc[(size_t)b*512 + j*8 + te];
            }
            __syncthreads();
            for (int m = tid; m < 640; m += NTHR) {
                int l = m >> 5, rem = m & 31, g = rem >> 3, b = rem & 7;
                int grow = (g < 2) ? (2*J + g) : (128 + 2*J + (g - 2));
                float acc = causal_b[l*256 + grow] + cond_b[l*256 + grow]
                          + pool[P_ZB + l*4 + g];
                const float* cw = cond_w + (size_t)(l*256 + grow)*64;
                const float* cf = pool + P_CF + b*66;
                for (int j = 0; j < 64; ++j) acc += cw[j]*cf[j];
                pool[P_CONDZ + l*32 + g*8 + b] = acc;
            }
            if (tid < 16) {
                int r = tid >> 3, b = tid & 7, row = 2*J + r;
                float acc = fc_b[row] + condf_b[row];
                const float* cw = condf_w + (size_t)row*64;
                const float* cf = pool + P_CF + b*66;
                for (int j = 0; j < 64; ++j) acc += cw[j]*cf[j];
                pool[P_SFC + r*8 + b] = acc;
            }
            __syncthreads();
        }

        // ---------------- h_0 closed form + immediate publish ----------------
        ++e; const int eh0 = e;
        {
            if (tid < 16) {
                int r = tid & 1, b = tid >> 1;
                float kf  = (t >= 1) ? 1.f : 0.f;
                float x0v = pool[P_XS + b];
                float x1v = pool[P_XS + 8 + b];
                float x2v = pool[P_XS + 16 + b];
                const float* zc = pool + P_Z0C;
                int g0 = r, g1 = 2 + r;
                float zg = kf*zc[g0*6+0] + zc[g0*6+1] + x2v*zc[g0*6+2]
                         + x1v*zc[g0*6+3] + x0v*zc[g0*6+4] + pool[P_CONDZ + g0*8 + b];
                float zo = kf*zc[g1*6+0] + zc[g1*6+1] + x2v*zc[g1*6+2]
                         + x1v*zc[g1*6+3] + x0v*zc[g1*6+4] + pool[P_CONDZ + g1*8 + b];
                pool[P_SL + r*8 + b] = (1.f/(1.f + expf(-zg))) * tanhf(zo);
            }
            // same wave as writers -> no barrier needed
            publish16(xb + (size_t)(eh0 & 3)*768, J, pool + P_SL, eh0);
        }
        // res_0 full (overlaps h_0 RTT)
        for (int m = tid; m < 1024; m += NTHR) {
            int b = m >> 7, r = m & 127;
            pool[P_RES0 + b*132 + r] =
                pool[P_FB + r] + pool[P_XS + 8 + b]*pool[P_WF0 + r]
                               + pool[P_XS + b]    *pool[P_WF1 + r];
        }
        // skip init + r2 init (closed form)
        if (tid < 16) {
            int r = tid >> 3, b = tid & 7;
            float x0v = pool[P_XS + b], x1v = pool[P_XS + 8 + b];
            pool[P_SKACC + r*8 + b] = pool[P_SKC + r*3] + x1v*pool[P_SKC + r*3 + 1]
                                                        + x0v*pool[P_SKC + r*3 + 2];
            int row = 2*J + r;
            pool[P_R2 + r*8 + b] = pool[P_FB + row] + x1v*pool[P_WF0 + row]
                                                    + x0v*pool[P_WF1 + row];
        }
        // no barrier needed: consumers of the above are all post-barA/barB

        // ---------------- layer loop ----------------
        for (int l = 0; l < LL; ++l) {
            int ehh;
            if (l == 0) {
                ehh = eh0;
            } else {
                // S1: z_l = W0.prev + W1.res_{l-1} + F_{l-1}.h_{l-1} + condz
                {
                    int g = tid >> 6, lane = tid & 63, b = lane >> 3, k = lane & 7;
                    const float* w0 = pool + P_WC + (l*4 + g)*256;
                    const float* pv = pool + P_PREVF + b*132;
                    const float* rs = ((l == 1) ? pool + P_RES0 : pool + P_RESF) + b*132;
                    const float* fm = pool + P_F + ((l-1)*4 + g)*128;
                    const float* hh = pool + P_HF + b*132;
                    float acc = 0.f;
                    #pragma unroll
                    for (int i = 0; i < 16; ++i) {
                        int j = k + 8*i;
                        acc += w0[j]*pv[j] + w0[128 + j]*rs[j] + fm[j]*hh[j];
                    }
                    acc += __shfl_xor(acc,1); acc += __shfl_xor(acc,2); acc += __shfl_xor(acc,4);
                    if (k == 0) pool[P_SZ + g*8 + b] = acc;
                }
                __syncthreads();
                // S3 + publish (wave 0, same-wave LDS ordering)
                ++e; ehh = e;
                if (tid < 16) {
                    int r = tid & 1, b = tid >> 1;
                    float g = pool[P_SZ + r*8 + b]     + pool[P_CONDZ + l*32 + r*8 + b];
                    float o = pool[P_SZ + (2+r)*8 + b] + pool[P_CONDZ + l*32 + (2+r)*8 + b];
                    pool[P_SL + r*8 + b] = (1.f/(1.f + expf(-g))) * tanhf(o);
                }
                publish16(xb + (size_t)(ehh & 3)*768, J, pool + P_SL, ehh);
            }
            // S6: stage this layer's res/skip weight rows (L2-resident)
            float wv0, wv1;
            {
                int r0 = tid >> 7, i0 = tid & 127;
                wv0 = res_w [(size_t)(l*128 + 2*J + r0)*128 + i0];
                wv1 = skip_w[(size_t)(l*128 + 2*J + r0)*128 + i0];
            }
            // S7: ring prefetch prev_{l+1}
            ull pfa = 0, pfb = 0;
            if (l <= 18) {
                int d = c_dil[l+1];
                if (t >= d) {
                    int slot = (t - d) & (2*d - 1);
                    const float* rp = ring + c_roff[l+1] + (size_t)slot*1024 + tid*4;
                    pfa = __hip_atomic_load((const ull*)rp,     __ATOMIC_RELAXED, __HIP_MEMORY_SCOPE_AGENT);
                    pfb = __hip_atomic_load((const ull*)(rp+2), __ATOMIC_RELAXED, __HIP_MEMORY_SCOPE_AGENT);
                }
            }
            // S7.5/S8: consume res_l (layer-old) + h_l (fused issue)
            if (l == 0) {
                consume16(xb + (size_t)(ehh & 3)*768, ehh, pool + P_HF, false);
            } else if (l <= 18) {
                consume_pair(xb + (size_t)(er_pending & 3)*768, er_pending, pool + P_RESF,
                             xb + (size_t)(ehh & 3)*768,        ehh,        pool + P_HF);
            } else {
                consume16(xb + (size_t)(ehh & 3)*768, ehh, pool + P_HF, false);
            }
            // S8.5: land staged weight rows
            pool[P_WST + tid] = wv0;
            pool[P_WST + 256 + tid] = wv1;
            __syncthreads();   // bar A
            // S10: dres slice (waves 0,1) + skip accum (waves 2,3)
            {
                int w = tid >> 6, lane = tid & 63, b = lane >> 3, k = lane & 7;
                int r = w & 1, isSkip = w >> 1;
                if (isSkip || l <= 18) {
                    const float* wr = pool + P_WST + (isSkip ? 256 : 0) + r*128;
                    const float* hh = pool + P_HF + b*132;
                    float acc = 0.f;
                    #pragma unroll
                    for (int i = 0; i < 16; ++i) { int j = k + 8*i; acc += wr[j]*hh[j]; }
                    acc += __shfl_xor(acc,1); acc += __shfl_xor(acc,2); acc += __shfl_xor(acc,4);
                    if (k == 0) {
                        if (isSkip) {
                            pool[P_SKACC + r*8 + b] += acc + pool[P_SKIPB + l*2 + r];
                        } else {
                            float v = pool[P_R2 + r*8 + b] + acc + pool[P_RESB + l*2 + r];
                            pool[P_R2 + r*8 + b] = v;
                            pool[P_SL + r*8 + b] = v;
                            int d = c_dil[l+1];
                            int slot = t & (2*d - 1);
                            float* wp = ring + c_roff[l+1] + (size_t)slot*1024 + b*128 + 2*J + r;
                            __hip_atomic_store(wp, v, __ATOMIC_RELAXED, __HIP_MEMORY_SCOPE_AGENT);
                        }
                    }
                }
            }
            // S10b: in-wave publishes (no barrier needed: same-wave data)
            {
                int w = tid >> 6, lane = tid & 63;
                if (l <= 17) {
                    ++e; er_pending = e;
                    if (w < 2 && lane < 3)
                        publish_half(xb + (size_t)(e & 3)*768, J, w,
                                     pool + P_SL + w*8, e, lane);
                } else if (l == 19) {
                    ++e; esk = e;   // skip vector finalized by waves 2,3 in S10
                    if (w >= 2 && lane < 3)
                        publish_half(xb + (size_t)(e & 3)*768, J, w - 2,
                                     pool + P_SKACC + (w - 2)*8, e, lane);
                }
            }
            // S11: land prev prefetch
            if (l <= 18) {
                int b = tid >> 5, c = (tid & 31)*4;
                union { ull u; float f[2]; } u0, u1;
                u0.u = pfa; u1.u = pfb;
                float* dp = pool + P_PREVF + b*132 + c;
                dp[0] = u0.f[0]; dp[1] = u0.f[1]; dp[2] = u1.f[0]; dp[3] = u1.f[1];
            }
            __syncthreads();   // bar B
        }

        // ---------------- head ----------------
        consume16(xb + (size_t)(esk & 3)*768, esk, pool + P_HF, false);   // skip gather
        __syncthreads();
        // fc: s = relu(skip).fc^T + sfc  (waves 0,1) + in-wave publish
        {
            int w = tid >> 6, lane = tid & 63, b = lane >> 3, k = lane & 7;
            if (w < 2) {
                const float* wr = pool + P_WFC + w*128;
                const float* sk = pool + P_HF + b*132;
                float acc = 0.f;
                #pragma unroll
                for (int i = 0; i < 16; ++i) { int j = k + 8*i; acc += wr[j]*fmaxf(sk[j], 0.f); }
                acc += __shfl_xor(acc,1); acc += __shfl_xor(acc,2); acc += __shfl_xor(acc,4);
                if (k == 0) pool[P_SL + w*8 + b] = acc + pool[P_SFC + w*8 + b];
            }
        }
        ++e;
        {
            int w = tid >> 6, lane = tid & 63;
            if (w < 2 && lane < 3)
                publish_half(xb + (size_t)(e & 3)*768, J, w, pool + P_SL + w*8, e, lane);
        }
        consume16(xb + (size_t)(e & 3)*768, e, pool + P_RESF, true);   // relu(s) gather
        __syncthreads();
        // logits rows + direct out-store + block-local argmax pair
        {
            int b = tid >> 5, g = (tid >> 3) & 3, k = tid & 7;
            const float* wr = pool + P_WLOG + g*128;
            const float* sv = pool + P_RESF + b*132;
            float acc = 0.f;
            #pragma unroll
            for (int i = 0; i < 16; ++i) { int j = k + 8*i; acc += wr[j]*sv[j]; }
            acc += __shfl_xor(acc,1); acc += __shfl_xor(acc,2); acc += __shfl_xor(acc,4);
            float v = acc + pool[P_LOGB + g];
            float best = (k == 0) ? v : -3.4e38f;
            int bi = 4*J + g;
            { float ov = __shfl_xor(best, 8);  int oi = __shfl_xor(bi, 8);
              if (ov > best || (ov == best && oi < bi)) { best = ov; bi = oi; } }
            { float ov = __shfl_xor(best, 16); int oi = __shfl_xor(bi, 16);
              if (ov > best || (ov == best && oi < bi)) { best = ov; bi = oi; } }
            if (k == 0) out[4096 + ((size_t)(t*BB + b))*256 + 4*J + g] = v;
            if ((tid & 31) == 0) { pool[P_SL + b] = best; pool[P_SL + 8 + b] = (float)bi; }
        }
        __syncthreads();
        ++e;
        publish16(xb + (size_t)(e & 3)*768, J, pool + P_SL, e);   // 64 (max,idx) pairs
        consume16(xb + (size_t)(e & 3)*768, e, pool + P_HF, false);
        __syncthreads();
        // final argmax reduce (idx-min tie-break == global first max) + x shift
        if (tid < 64) {
            int b = tid >> 3, j0 = tid & 7;
            float best = -3.4e38f; float bidx = 0.f;
            #pragma unroll
            for (int k2 = 0; k2 < 8; ++k2) {
                int j = j0*8 + k2;
                float v  = pool[P_HF + b*132 + 2*j];
                float id = pool[P_HF + b*132 + 2*j + 1];
                if (v > best || (v == best && id < bidx)) { best = v; bidx = id; }
            }
            #pragma unroll
            for (int m = 4; m >= 1; m >>= 1) {
                float ov = __shfl_xor(best, m); float oi = __shfl_xor(bidx, m);
                if (ov > best || (ov == best && oi < bidx)) { best = ov; bidx = oi; }
            }
            if (j0 == 0) {
                if (J == 0) out[t*BB + b] = bidx;
                pool[P_XS + 16 + b] = pool[P_XS + 8 + b];
                pool[P_XS + 8 + b]  = pool[P_XS + b];
                pool[P_XS + b]      = bidx*(1.f/255.f) - 0.5f;
            }
        }
        __syncthreads();
    }
}

// ============================================================
extern "C" void kernel_launch(void* const* d_in, const int* in_sizes, int n_in,
                              void* d_out, int out_size, void* d_ws, size_t ws_size,
                              hipStream_t stream) {
    const float* enc      = (const float*)d_in[0];
    const float* first_w  = (const float*)d_in[1];
    const float* first_b  = (const float*)d_in[2];
    const float* causal_w = (const float*)d_in[3];
    const float* causal_b = (const float*)d_in[4];
    const float* cond_w   = (const float*)d_in[5];
    const float* cond_b   = (const float*)d_in[6];
    const float* res_w    = (const float*)d_in[7];
    const float* res_b    = (const float*)d_in[8];
    const float* skip_w   = (const float*)d_in[9];
    const float* skip_b   = (const float*)d_in[10];
    const float* skipc_w  = (const float*)d_in[11];
    const float* skipc_b  = (const float*)d_in[12];
    const float* fc_w     = (const float*)d_in[13];
    const float* fc_b     = (const float*)d_in[14];
    const float* condf_w  = (const float*)d_in[15];
    const float* condf_b  = (const float*)d_in[16];
    const float* logits_w = (const float*)d_in[17];
    const float* logits_b = (const float*)d_in[18];

    float* wsf = (float*)d_ws;
    float* out = (float*)d_out;

    wn_gen<<<NBLK, NTHR, POOL_FL*4, stream>>>(
        enc, first_w, first_b, causal_w, causal_b, cond_w, cond_b,
        res_w, res_b, skip_w, skip_b, skipc_w, skipc_b, fc_w, fc_b,
        condf_w, condf_b, logits_w, logits_b, wsf, out);
}